// Round 5
// baseline (382.636 us; speedup 1.0000x reference)
//
#include <hip/hip_runtime.h>

#define NUM_NODES 50000
#define WINDOW 8
#define DIM 256
#define BATCH 8192
#define NROWS (NUM_NODES * WINDOW)          // 400000 rows
#define BANK4 ((long)NROWS * (DIM / 4))     // 25.6M float4

// ---- K_A: ALL control-plane work in ONE single-block dispatch -----------------------
// Zero count, init winner map, count occurrences, classify, rank duplicates (LDS),
// write the (node,slot)->batch-element winner map.
// Single block => one XCD's L2 => atomics + atomic-reads are coherent.
__global__ void __launch_bounds__(1024)
prep_kernel(const int* __restrict__ idx, const int* __restrict__ ptr,
            int* __restrict__ count, short* __restrict__ winner) {
    __shared__ int spos [BATCH];    // 32 KiB  batch position of each duplicate
    __shared__ int snode[BATCH];    // 32 KiB  its node id
    __shared__ int scnt [BATCH];    // 32 KiB  its node's total count
    __shared__ int sndup;
    const int tid = threadIdx.x;

    // phase 0: init accumulators (ws persists across replays -> re-init every call)
    int* winner_i = (int*)winner;                       // two -1 shorts per int
    for (int i = tid; i < NUM_NODES; i += 1024) count[i] = 0;
    for (int i = tid; i < NROWS / 2; i += 1024) winner_i[i] = 0xFFFFFFFF;
    if (tid == 0) sndup = 0;
    __syncthreads();

    // phase 1: per-node occurrence count (order-independent)
    for (int bi = tid; bi < BATCH; bi += 1024) atomicAdd(&count[idx[bi]], 1);
    __syncthreads();

    // phase 2: classify. atomicAdd(p,0) = coherent read (plain loads could hit the
    // stale zero-valued lines this block itself put in L1 during phase 0).
    for (int bi = tid; bi < BATCH; bi += 1024) {
        int node = idx[bi];
        int c    = atomicAdd(&count[node], 0);
        if (c == 1) {                                   // rank 0, always a winner
            winner[node * WINDOW + (ptr[node] & (WINDOW - 1))] = (short)bi;
        } else {                                        // defer: rank among dups
            int k = atomicAdd(&sndup, 1);
            spos[k] = bi; snode[k] = node; scnt[k] = c;
        }
    }
    __syncthreads();

    // phase 3: rank duplicates, LDS-only O(n^2), n ~ 1.2K expected (max 8192).
    // rank over the dup list == full batch rank (all occurrences of a dup node are
    // in the list). Winner iff rank >= c-8 (last writer per slot); winners of one
    // node get distinct slots => unique writer per (node,slot).
    const int n = sndup;
    for (int k = tid; k < n; k += 1024) {
        int p = spos[k], node = snode[k], rank = 0;
        for (int m = 0; m < n; ++m)
            rank += (spos[m] < p && snode[m] == node);
        if (rank >= scnt[k] - WINDOW)
            winner[node * WINDOW + ((ptr[node] + rank) & (WINDOW - 1))] = (short)p;
    }
}

// ---- K_B: the HBM-bound pass — fused copy + winner-select + ptr_new -----------------
__global__ void __launch_bounds__(256)
fused_copy_kernel(const float4* __restrict__ bank4, const float* __restrict__ ts,
                  const float4* __restrict__ nrep4, const float* __restrict__ t,
                  const short* __restrict__ winner,
                  const int* __restrict__ ptr, const int* __restrict__ count,
                  float4* __restrict__ out_bank4, float* __restrict__ out_ts,
                  float* __restrict__ out_ptr) {
    const long tid = (long)blockIdx.x * blockDim.x + threadIdx.x;
    const long nth = (long)gridDim.x * blockDim.x;
    for (long i = tid; i < BANK4; i += nth) {
        int row = (int)(i >> 6);                        // 64 float4 per row
        int w   = winner[row];                          // wave-uniform-ish, L1/L2 hit
        float4 v = (w >= 0) ? nrep4[(long)w * (DIM / 4) + (i & 63)] : bank4[i];
        out_bank4[i] = v;
        if ((i & 63) == 0)
            out_ts[row] = (w >= 0) ? t[w] : ts[row];
    }
    // ptr_new = float(ptr + count); plain loads are safe cross-kernel (dispatch
    // boundary does the L2 release/acquire).
    if (tid < NUM_NODES) out_ptr[tid] = (float)(ptr[tid] + count[tid]);
}

extern "C" void kernel_launch(void* const* d_in, const int* in_sizes, int n_in,
                              void* d_out, int out_size, void* d_ws, size_t ws_size,
                              hipStream_t stream) {
    const float* bank       = (const float*)d_in[0];
    const float* timestamps = (const float*)d_in[1];
    const float* nrep       = (const float*)d_in[2];
    const float* t          = (const float*)d_in[3];
    const int*   ptr        = (const int*)  d_in[4];
    const int*   idx        = (const int*)  d_in[5];

    float* out_bank = (float*)d_out;
    float* out_ts   = out_bank + (size_t)NUM_NODES * WINDOW * DIM;
    float* out_ptr  = out_ts   + (size_t)NUM_NODES * WINDOW;

    // ws layout: count[50000] int | winner[400000] short (1 MB total)
    int*   count  = (int*)d_ws;
    short* winner = (short*)(count + NUM_NODES);

    prep_kernel<<<1, 1024, 0, stream>>>(idx, ptr, count, winner);

    fused_copy_kernel<<<2048, 256, 0, stream>>>(
        (const float4*)bank, timestamps, (const float4*)nrep, t, winner,
        ptr, count, (float4*)out_bank, out_ts, out_ptr);
}

// Round 7
// 265.112 us; speedup vs baseline: 1.4433x; 1.4433x over previous
//
#include <hip/hip_runtime.h>

#define NUM_NODES 50000
#define WINDOW 8
#define DIM 256
#define BATCH 8192
#define NROWS (NUM_NODES * WINDOW)          // 400000 rows
#define ROW4  (DIM / 4)                     // 64 float4 per row
#define BANK4 ((long)NROWS * ROW4)          // 25.6M float4
#define WINNER_INTS (NROWS / 2)             // winner map as ints (2 shorts each)

typedef float f4 __attribute__((ext_vector_type(4)));   // native vector: NT-builtin OK

// ws layout (ints): count[50000] | winner[200000] | dupN[1] | duplist[8192]

// ---- K0: init all accumulators, one wide dispatch (977 blocks) ----------------------
__global__ void __launch_bounds__(256)
init_kernel(int* __restrict__ ws) {
    int i = blockIdx.x * 256 + threadIdx.x;
    if (i < NUM_NODES) ws[i] = 0;                                   // count = 0
    else if (i < NUM_NODES + WINNER_INTS) ws[i] = 0xFFFFFFFF;       // winner = -1,-1
    else if (i == NUM_NODES + WINNER_INTS) ws[i] = 0;               // dupN = 0
}

// ---- K1: per-node occurrence count (order-independent atomics) ----------------------
__global__ void __launch_bounds__(256)
count_kernel(const int* __restrict__ idx, int* __restrict__ count) {
    int bi = blockIdx.x * 256 + threadIdx.x;
    if (bi < BATCH) atomicAdd(&count[idx[bi]], 1);
}

// ---- K2: classify (unique nodes -> direct winner) + ptr_new fused -------------------
// count==1 => rank 0, always a winner. count>1 => defer to K3 (append order
// irrelevant: K3 ranks by batch position, deterministic).
__global__ void __launch_bounds__(256)
classify_kernel(const int* __restrict__ idx, const int* __restrict__ ptr,
                const int* __restrict__ count, short* __restrict__ winner,
                int* __restrict__ duplist, int* __restrict__ dupN,
                float* __restrict__ out_ptr) {
    int i = blockIdx.x * 256 + threadIdx.x;          // grid covers 50176 threads
    if (i < NUM_NODES) out_ptr[i] = (float)(ptr[i] + count[i]);   // exact in f32
    if (i < BATCH) {
        int node = idx[i];
        int c    = count[node];
        if (c == 1) winner[node * WINDOW + (ptr[node] & (WINDOW - 1))] = (short)i;
        else        duplist[atomicAdd(dupN, 1)] = i;
    }
}

// ---- K3: rank duplicates — LDS-staged O(n^2), 32 wide blocks (n ~ 1.3K, max 8192) ---
// rank over dup list == full batch rank (all occurrences of a dup node are listed).
// Winner iff rank >= c-8 (last writer per slot); winners get distinct slots.
__global__ void __launch_bounds__(256)
dup_rank_kernel(const int* __restrict__ idx, const int* __restrict__ ptr,
                const int* __restrict__ count,
                const int* __restrict__ duplist, const int* __restrict__ dupN,
                short* __restrict__ winner) {
    __shared__ int spos [BATCH];           // 32 KiB
    __shared__ int snode[BATCH];           // 32 KiB
    int n = *dupN;
    for (int k = threadIdx.x; k < n; k += 256) {
        int p = duplist[k];
        spos [k] = p;
        snode[k] = idx[p];
    }
    __syncthreads();

    int k = blockIdx.x * 256 + threadIdx.x;
    if (k >= n) return;
    int p    = spos[k];
    int node = snode[k];
    int rank = 0;
    for (int m = 0; m < n; ++m)
        rank += (spos[m] < p && snode[m] == node);

    if (rank >= count[node] - WINDOW)
        winner[node * WINDOW + ((ptr[node] + rank) & (WINDOW - 1))] = (short)p;
}

// ---- K4: the HBM-bound pass — single-pass copy/select, 1 thread = 1 float4 ----------
// 64 lanes = 1 row => winner[row] is a broadcast short load; branch is wave-uniform.
// NT load/store on the 410 MB streams (no reuse, keep L2 for winner/nrep/t).
__global__ void __launch_bounds__(256)
copy_kernel(const f4* __restrict__ bank4, const float* __restrict__ ts,
            const f4* __restrict__ nrep4, const float* __restrict__ t,
            const short* __restrict__ winner,
            f4* __restrict__ out_bank4, float* __restrict__ out_ts) {
    long gid = (long)blockIdx.x * 256 + threadIdx.x;    // < 25.6M
    int  row = (int)(gid >> 6);
    int  off = (int)(gid & 63);
    int  w   = winner[row];
    f4 v;
    if (w >= 0) v = nrep4[(long)w * ROW4 + off];
    else        v = __builtin_nontemporal_load(&bank4[gid]);
    __builtin_nontemporal_store(v, &out_bank4[gid]);
    if (off == 0) out_ts[row] = (w >= 0) ? t[w] : ts[row];
}

extern "C" void kernel_launch(void* const* d_in, const int* in_sizes, int n_in,
                              void* d_out, int out_size, void* d_ws, size_t ws_size,
                              hipStream_t stream) {
    const float* bank       = (const float*)d_in[0];
    const float* timestamps = (const float*)d_in[1];
    const float* nrep       = (const float*)d_in[2];
    const float* t          = (const float*)d_in[3];
    const int*   ptr        = (const int*)  d_in[4];
    const int*   idx        = (const int*)  d_in[5];

    float* out_bank = (float*)d_out;
    float* out_ts   = out_bank + (size_t)NUM_NODES * WINDOW * DIM;
    float* out_ptr  = out_ts   + (size_t)NUM_NODES * WINDOW;

    int*   count   = (int*)d_ws;
    short* winner  = (short*)(count + NUM_NODES);
    int*   dupN    = count + NUM_NODES + WINNER_INTS;
    int*   duplist = dupN + 1;

    const int initN = NUM_NODES + WINNER_INTS + 1;       // 250001 ints
    init_kernel    <<<(initN + 255) / 256, 256, 0, stream>>>((int*)d_ws);
    count_kernel   <<<(BATCH + 255) / 256, 256, 0, stream>>>(idx, count);
    classify_kernel<<<(NUM_NODES + 255) / 256, 256, 0, stream>>>(idx, ptr, count,
                                                winner, duplist, dupN, out_ptr);
    dup_rank_kernel<<<(BATCH + 255) / 256, 256, 0, stream>>>(idx, ptr, count,
                                                duplist, dupN, winner);

    copy_kernel<<<(int)(BANK4 / 256), 256, 0, stream>>>(
        (const f4*)bank, timestamps, (const f4*)nrep, t, winner,
        (f4*)out_bank, out_ts);
}